// Round 3
// baseline (94.429 us; speedup 1.0000x reference)
//
#include <hip/hip_runtime.h>
#include <math.h>

#define BS 4096
#define C_CLS 16384
#define D 128
#define NS 8  // batch splits for neg matmul
// exp(32*d - 32.8) = 2^(d*KE - BE)
#define KE 46.16624130844683f
#define BE 47.32039734115807f

typedef __attribute__((ext_vector_type(8))) short short8;
typedef __attribute__((ext_vector_type(4))) float f32x4;

__device__ inline float bf2f(unsigned short h) {
    return __uint_as_float(((unsigned)h) << 16);
}
__device__ inline unsigned short f2bf(float f) {
    unsigned u = __float_as_uint(f);
    u += 0x7FFF + ((u >> 16) & 1);  // RNE
    return (unsigned short)(u >> 16);
}
__device__ inline float fast_exp2(float x) {
#if __has_builtin(__builtin_amdgcn_exp2f)
    return __builtin_amdgcn_exp2f(x);
#else
    return exp2f(x);
#endif
}
__device__ inline float softplus(float x) {
    return fmaxf(x, 0.0f) + log1pf(__expf(-fabsf(x)));
}

// ---------- fused normalize (batch + proxies) + ws zeroing ----------
__global__ __launch_bounds__(256) void normalize_all(const float* __restrict__ batch,
                                                     const float* __restrict__ proxies,
                                                     short* __restrict__ bbf,
                                                     short* __restrict__ pbf,
                                                     float* __restrict__ acc,
                                                     float* __restrict__ negSub) {
    const int w = threadIdx.x >> 6, lane = threadIdx.x & 63;
    const int row = blockIdx.x * 4 + w;
    const float* src;
    short* dst;
    int r;
    if (row < BS) {
        src = batch; dst = bbf; r = row;
    } else {
        src = proxies; dst = pbf; r = row - BS;
    }
    float2 v = ((const float2*)(src + (size_t)r * D))[lane];
    float ss = v.x * v.x + v.y * v.y;
#pragma unroll
    for (int off = 32; off; off >>= 1) ss += __shfl_xor(ss, off);
    float inv = rsqrtf(ss);
    ushort2 o;
    o.x = f2bf(v.x * inv);
    o.y = f2bf(v.y * inv);
    ((ushort2*)(dst + (size_t)r * D))[lane] = o;

    if (blockIdx.x < 64) negSub[blockIdx.x * 256 + threadIdx.x] = 0.0f;
    if (blockIdx.x == 0 && threadIdx.x < 4) acc[threadIdx.x] = 0.0f;
}

// ---------- NEG unmasked matmul + per-proxy (sum, max, min) ----------
// block: 4 waves x 32 proxies (2 tiles of 16) = 128 proxies; grid = 128 x NS
__global__ __launch_bounds__(256) void neg_mm(const short* __restrict__ pbf,
                                              const short* __restrict__ bbf,
                                              float* __restrict__ S,
                                              float* __restrict__ Mx,
                                              float* __restrict__ Mn) {
    const int tid = threadIdx.x;
    const int w = tid >> 6, lane = tid & 63, l16 = lane & 15, g = lane >> 4;
    const int pb = (blockIdx.x & 127) * 128;
    const int sp = blockIdx.x >> 7;
    const int wbase = pb + w * 32;

    short8 a[2][4];
#pragma unroll
    for (int t = 0; t < 2; t++)
#pragma unroll
        for (int kk = 0; kk < 4; kk++)
            a[t][kk] = *(const short8*)(pbf + (size_t)(wbase + t * 16 + l16) * D + kk * 32 + g * 8);

    float s[2][4], mx[2][4], mn[2][4];
#pragma unroll
    for (int t = 0; t < 2; t++)
#pragma unroll
        for (int r = 0; r < 4; r++) {
            s[t][r] = 0.0f; mx[t][r] = -INFINITY; mn[t][r] = INFINITY;
        }

    const int ibeg = sp * (BS / NS);
    const int iend = ibeg + BS / NS;

    short8 b[4];
#pragma unroll
    for (int kk = 0; kk < 4; kk++)
        b[kk] = *(const short8*)(bbf + (size_t)(ibeg + l16) * D + kk * 32 + g * 8);

    for (int i0 = ibeg; i0 < iend; i0 += 16) {
        // prefetch next chunk's B fragment
        short8 bn[4];
        const int inext = (i0 + 16 < iend) ? (i0 + 16) : ibeg;
#pragma unroll
        for (int kk = 0; kk < 4; kk++)
            bn[kk] = *(const short8*)(bbf + (size_t)(inext + l16) * D + kk * 32 + g * 8);

        f32x4 acc0 = {0.0f, 0.0f, 0.0f, 0.0f};
        f32x4 acc1 = {0.0f, 0.0f, 0.0f, 0.0f};
#pragma unroll
        for (int kk = 0; kk < 4; kk++)
            acc0 = __builtin_amdgcn_mfma_f32_16x16x32_bf16(a[0][kk], b[kk], acc0, 0, 0, 0);
#pragma unroll
        for (int kk = 0; kk < 4; kk++)
            acc1 = __builtin_amdgcn_mfma_f32_16x16x32_bf16(a[1][kk], b[kk], acc1, 0, 0, 0);

#pragma unroll
        for (int r = 0; r < 4; r++) {
            float d0 = acc0[r], d1 = acc1[r];
            s[0][r] += fast_exp2(fmaf(d0, KE, -BE));
            s[1][r] += fast_exp2(fmaf(d1, KE, -BE));
            mx[0][r] = fmaxf(mx[0][r], d0);
            mx[1][r] = fmaxf(mx[1][r], d1);
            mn[0][r] = fminf(mn[0][r], d0);
            mn[1][r] = fminf(mn[1][r], d1);
        }
#pragma unroll
        for (int kk = 0; kk < 4; kk++) b[kk] = bn[kk];
    }

    // reduce across the 16 batch-column lanes (l16); stays within same g
#pragma unroll
    for (int off = 1; off < 16; off <<= 1)
#pragma unroll
        for (int t = 0; t < 2; t++)
#pragma unroll
            for (int r = 0; r < 4; r++) {
                s[t][r] += __shfl_xor(s[t][r], off);
                mx[t][r] = fmaxf(mx[t][r], __shfl_xor(mx[t][r], off));
                mn[t][r] = fminf(mn[t][r], __shfl_xor(mn[t][r], off));
            }
    if (l16 == 0) {
#pragma unroll
        for (int t = 0; t < 2; t++)
#pragma unroll
            for (int r = 0; r < 4; r++) {
                int row = wbase + t * 16 + g * 4 + r;
                int idx = row * NS + sp;
                S[idx] = s[t][r];
                Mx[idx] = mx[t][r];
                Mn[idx] = mn[t][r];
            }
    }
}

// ---------- pos scan (per column j) + neg corrections (per row i) ----------
__global__ __launch_bounds__(256) void corr_pos(const short* __restrict__ pbf,
                                                const short* __restrict__ bbf,
                                                const int* __restrict__ labels,
                                                float* __restrict__ negSub,
                                                float* __restrict__ posS,
                                                float* __restrict__ posMx,
                                                float* __restrict__ posMn,
                                                float* __restrict__ posCnt) {
    const int w = threadIdx.x >> 6, lane = threadIdx.x & 63;
    if (blockIdx.x >= 1024) {
        // neg correction: subtract exp term for pair (i, labels[i])
        const int i = (blockIdx.x - 1024) * 4 + w;
        const int lab = labels[i];
        ushort2 av = ((const ushort2*)(bbf + (size_t)i * D))[lane];
        ushort2 pv = ((const ushort2*)(pbf + (size_t)lab * D))[lane];
        float d = bf2f(av.x) * bf2f(pv.x) + bf2f(av.y) * bf2f(pv.y);
#pragma unroll
        for (int off = 32; off; off >>= 1) d += __shfl_xor(d, off);
        if (lane == 0) atomicAdd(&negSub[lab], fast_exp2(fmaf(d, KE, -BE)));
    } else {
        // pos: one wave per column j
        const int j = blockIdx.x * 4 + w;
        const int labj = labels[j];
        ushort2 pv = ((const ushort2*)(pbf + (size_t)labj * D))[lane];
        const float p0 = bf2f(pv.x), p1 = bf2f(pv.y);
        float s = 0.0f, mxw = -INFINITY, mnw = INFINITY, c = 0.0f;
        for (int i0 = 0; i0 < BS; i0 += 256) {
            int4 lv = ((const int4*)labels)[(i0 >> 2) + lane];
#pragma unroll
            for (int comp = 0; comp < 4; comp++) {
                int lc = (comp == 0) ? lv.x : (comp == 1) ? lv.y : (comp == 2) ? lv.z : lv.w;
                unsigned long long bits = __ballot(lc == labj);
                while (bits) {
                    int L = __builtin_ctzll(bits);
                    bits &= bits - 1;
                    int i = i0 + 4 * L + comp;
                    ushort2 bv = ((const ushort2*)(bbf + (size_t)i * D))[lane];
                    float d = bf2f(bv.x) * p0 + bf2f(bv.y) * p1;
#pragma unroll
                    for (int off = 32; off; off >>= 1) d += __shfl_xor(d, off);
                    float wv = fmaf(d, -32.0f, 3.2f);
                    s += __expf(wv);
                    mxw = fmaxf(mxw, wv);
                    mnw = fminf(mnw, wv);
                    c += 1.0f;
                }
            }
        }
        if (lane == 0) {
            posS[j] = s; posMx[j] = mxw; posMn[j] = mnw; posCnt[j] = c;
        }
    }
}

// ---------- final: combine partials, softplus, masked mean accumulate ----------
__global__ __launch_bounds__(256) void final_reduce(const float* __restrict__ S,
                                                    const float* __restrict__ Mx,
                                                    const float* __restrict__ Mn,
                                                    const float* __restrict__ negSub,
                                                    const float* __restrict__ posS,
                                                    const float* __restrict__ posMx,
                                                    const float* __restrict__ posMn,
                                                    const float* __restrict__ posCnt,
                                                    float* __restrict__ acc) {
    const int n = blockIdx.x * 256 + threadIdx.x;
    float add = 0.0f, cnt = 0.0f;
    int slot;
    if (n < C_CLS) {
        slot = 2;
        float s = 0.0f, mxd = -INFINITY, mnd = INFINITY;
#pragma unroll
        for (int p = 0; p < NS; p++) {
            s += S[n * NS + p];
            mxd = fmaxf(mxd, Mx[n * NS + p]);
            mnd = fminf(mnd, Mn[n * NS + p]);
        }
        s = fmaxf(s - negSub[n], 1e-30f);
        float mxw = fmaf(mxd, 32.0f, 3.2f);
        float mnw = fmaf(mnd, 32.0f, 3.2f);
        bool nz = (mxw + mnw) != 0.0f;
        if (nz) {
            float lse = logf(s) + 36.0f;
            add = softplus(lse);
            cnt = 1.0f;
        }
    } else {
        slot = 0;
        int j = n - C_CLS;
        float s = posS[j], mxw = posMx[j], mnw = posMn[j], c = posCnt[j];
        float maxm = (c < (float)BS) ? fmaxf(mxw, 0.0f) : mxw;
        float minm = (c < (float)BS) ? fminf(mnw, 0.0f) : mnw;
        bool nz = (maxm + minm) != 0.0f;
        if (nz) {
            float lse = logf(s);
            add = softplus(lse);
            cnt = 1.0f;
        }
    }
#pragma unroll
    for (int off = 32; off; off >>= 1) {
        add += __shfl_xor(add, off);
        cnt += __shfl_xor(cnt, off);
    }
    if ((threadIdx.x & 63) == 0) {
        atomicAdd(&acc[slot], add);
        atomicAdd(&acc[slot + 1], cnt);
    }
}

__global__ void combine_kernel(const float* __restrict__ acc, float* __restrict__ out) {
    out[0] = acc[0] / fmaxf(acc[1], 1.0f) + acc[2] / fmaxf(acc[3], 1.0f);
}

// ---------- launch ----------
extern "C" void kernel_launch(void* const* d_in, const int* in_sizes, int n_in,
                              void* d_out, int out_size, void* d_ws, size_t ws_size,
                              hipStream_t stream) {
    const float* batch = (const float*)d_in[0];
    const float* proxies = (const float*)d_in[1];
    const int* labels = (const int*)d_in[2];
    float* out = (float*)d_out;

    char* ws = (char*)d_ws;
    float* acc = (float*)ws;
    short* bbf = (short*)(ws + 256);
    short* pbf = (short*)(ws + 256 + (size_t)BS * D * 2);
    char* p = ws + 256 + (size_t)(BS + C_CLS) * D * 2;
    float* negS = (float*)p;             p += (size_t)C_CLS * NS * 4;
    float* negMx = (float*)p;            p += (size_t)C_CLS * NS * 4;
    float* negMn = (float*)p;            p += (size_t)C_CLS * NS * 4;
    float* negSub = (float*)p;           p += (size_t)C_CLS * 4;
    float* posS = (float*)p;             p += (size_t)BS * 4;
    float* posMx = (float*)p;            p += (size_t)BS * 4;
    float* posMn = (float*)p;            p += (size_t)BS * 4;
    float* posCnt = (float*)p;

    normalize_all<<<(BS + C_CLS) / 4, 256, 0, stream>>>(batch, proxies, bbf, pbf, acc, negSub);
    neg_mm<<<128 * NS, 256, 0, stream>>>(pbf, bbf, negS, negMx, negMn);
    corr_pos<<<2048, 256, 0, stream>>>(pbf, bbf, labels, negSub, posS, posMx, posMn, posCnt);
    final_reduce<<<(C_CLS + BS) / 256, 256, 0, stream>>>(negS, negMx, negMn, negSub,
                                                         posS, posMx, posMn, posCnt, acc);
    combine_kernel<<<1, 1, 0, stream>>>(acc, out);
}

// Round 4
// 65.728 us; speedup vs baseline: 1.4367x; 1.4367x over previous
//
#include <hip/hip_runtime.h>
#include <math.h>

#define BS 4096
#define C_CLS 16384
#define D 128
#define NS 16  // batch splits for neg matmul: each split = 256 rows = 4 rounds of 64
// exp(32*d - 32.8) = 2^(d*KE - BE)
#define KE 46.16624130844683f
#define BE 47.32039734115807f

typedef __attribute__((ext_vector_type(8))) short short8;
typedef __attribute__((ext_vector_type(4))) float f32x4;

__device__ inline float bf2f(unsigned short h) {
    return __uint_as_float(((unsigned)h) << 16);
}
__device__ inline unsigned short f2bf(float f) {
    unsigned u = __float_as_uint(f);
    u += 0x7FFF + ((u >> 16) & 1);  // RNE
    return (unsigned short)(u >> 16);
}
__device__ inline float fast_exp2(float x) {
#if __has_builtin(__builtin_amdgcn_exp2f)
    return __builtin_amdgcn_exp2f(x);
#else
    return exp2f(x);
#endif
}
__device__ inline float softplus(float x) {
    return fmaxf(x, 0.0f) + log1pf(__expf(-fabsf(x)));
}

// ---------- fused normalize (batch + proxies) + ws zeroing ----------
__global__ __launch_bounds__(256) void normalize_all(const float* __restrict__ batch,
                                                     const float* __restrict__ proxies,
                                                     short* __restrict__ bbf,
                                                     short* __restrict__ pbf,
                                                     float* __restrict__ acc,
                                                     float* __restrict__ negSub) {
    const int w = threadIdx.x >> 6, lane = threadIdx.x & 63;
    const int row = blockIdx.x * 4 + w;
    const float* src;
    short* dst;
    int r;
    if (row < BS) {
        src = batch; dst = bbf; r = row;
    } else {
        src = proxies; dst = pbf; r = row - BS;
    }
    float2 v = ((const float2*)(src + (size_t)r * D))[lane];
    float ss = v.x * v.x + v.y * v.y;
#pragma unroll
    for (int off = 32; off; off >>= 1) ss += __shfl_xor(ss, off);
    float inv = rsqrtf(ss);
    ushort2 o;
    o.x = f2bf(v.x * inv);
    o.y = f2bf(v.y * inv);
    ((ushort2*)(dst + (size_t)r * D))[lane] = o;

    if (blockIdx.x < 64) negSub[blockIdx.x * 256 + threadIdx.x] = 0.0f;
    if (blockIdx.x == 0 && threadIdx.x < 4) acc[threadIdx.x] = 0.0f;
}

// ---------- NEG unmasked matmul + per-proxy exp-sum ----------
// Block: 4 waves; wave owns 4 proxy-tiles (64 proxies) -> block owns 256.
// Grid: 64 proxy-groups x NS splits. Per split: 256 batch rows, 4 rounds of 64.
// B staged in LDS in per-lane fragment order: granule (tile*4+kk)*64+lane, 16B.
// Conflict-free on both ds_write and ds_read; shared by all 4 waves.
__global__ __launch_bounds__(256) void neg_mm(const short* __restrict__ pbf,
                                              const short* __restrict__ bbf,
                                              float* __restrict__ S) {
    __shared__ short8 frag[16 * 64];  // 4 tiles x 4 kk x 64 lanes x 16B = 16 KB

    const int tid = threadIdx.x;
    const int w = tid >> 6, lane = tid & 63, l16 = lane & 15, g = lane >> 4;
    const int pg = blockIdx.x & 63;   // proxy group (256 proxies)
    const int sp = blockIdx.x >> 6;   // split 0..NS-1
    const int wbase = pg * 256 + w * 64;

    // A fragments: 4 proxy tiles, held in registers for the whole kernel
    short8 a[4][4];
#pragma unroll
    for (int pt = 0; pt < 4; pt++)
#pragma unroll
        for (int kk = 0; kk < 4; kk++)
            a[pt][kk] = *(const short8*)(pbf + (size_t)(wbase + pt * 16 + l16) * D + kk * 32 + g * 8);

    float s[4][4];
#pragma unroll
    for (int pt = 0; pt < 4; pt++)
#pragma unroll
        for (int r = 0; r < 4; r++) s[pt][r] = 0.0f;

    const int ibeg = sp * (BS / NS);

    // preload round 0: wave w stages tile w (rows ibeg + w*16 + l16)
    short8 breg[4];
#pragma unroll
    for (int kk = 0; kk < 4; kk++)
        breg[kk] = *(const short8*)(bbf + (size_t)(ibeg + w * 16 + l16) * D + kk * 32 + g * 8);

    for (int rnd = 0; rnd < 4; rnd++) {
        __syncthreads();  // previous round's frag reads complete
#pragma unroll
        for (int kk = 0; kk < 4; kk++) frag[(w * 4 + kk) * 64 + lane] = breg[kk];
        __syncthreads();  // frag ready
        if (rnd < 3) {
            const int inext = ibeg + (rnd + 1) * 64 + w * 16 + l16;
#pragma unroll
            for (int kk = 0; kk < 4; kk++)
                breg[kk] = *(const short8*)(bbf + (size_t)inext * D + kk * 32 + g * 8);
        }
#pragma unroll
        for (int bt = 0; bt < 4; bt++) {
            short8 b[4];
#pragma unroll
            for (int kk = 0; kk < 4; kk++) b[kk] = frag[(bt * 4 + kk) * 64 + lane];
            f32x4 acc[4];
#pragma unroll
            for (int pt = 0; pt < 4; pt++) {
                acc[pt] = (f32x4){0.0f, 0.0f, 0.0f, 0.0f};
#pragma unroll
                for (int kk = 0; kk < 4; kk++)
                    acc[pt] = __builtin_amdgcn_mfma_f32_16x16x32_bf16(a[pt][kk], b[kk], acc[pt], 0, 0, 0);
            }
#pragma unroll
            for (int pt = 0; pt < 4; pt++)
#pragma unroll
                for (int r = 0; r < 4; r++)
                    s[pt][r] += fast_exp2(fmaf(acc[pt][r], KE, -BE));
        }
    }

    // reduce the 16 batch-column lanes (same g group)
#pragma unroll
    for (int off = 1; off < 16; off <<= 1)
#pragma unroll
        for (int pt = 0; pt < 4; pt++)
#pragma unroll
            for (int r = 0; r < 4; r++) s[pt][r] += __shfl_xor(s[pt][r], off);

    if (l16 == 0) {
#pragma unroll
        for (int pt = 0; pt < 4; pt++)
#pragma unroll
            for (int r = 0; r < 4; r++) {
                int row = wbase + pt * 16 + g * 4 + r;
                S[(size_t)row * NS + sp] = s[pt][r];
            }
    }
}

// ---------- pos scan (per column j) + neg corrections (per row i) ----------
__global__ __launch_bounds__(256) void corr_pos(const short* __restrict__ pbf,
                                                const short* __restrict__ bbf,
                                                const int* __restrict__ labels,
                                                float* __restrict__ negSub,
                                                float* __restrict__ posS,
                                                float* __restrict__ posMx,
                                                float* __restrict__ posMn,
                                                float* __restrict__ posCnt) {
    const int w = threadIdx.x >> 6, lane = threadIdx.x & 63;
    if (blockIdx.x >= 1024) {
        // neg correction: subtract exp term for pair (i, labels[i])
        const int i = (blockIdx.x - 1024) * 4 + w;
        const int lab = labels[i];
        ushort2 av = ((const ushort2*)(bbf + (size_t)i * D))[lane];
        ushort2 pv = ((const ushort2*)(pbf + (size_t)lab * D))[lane];
        float d = bf2f(av.x) * bf2f(pv.x) + bf2f(av.y) * bf2f(pv.y);
#pragma unroll
        for (int off = 32; off; off >>= 1) d += __shfl_xor(d, off);
        if (lane == 0) atomicAdd(&negSub[lab], fast_exp2(fmaf(d, KE, -BE)));
    } else {
        // pos: one wave per column j
        const int j = blockIdx.x * 4 + w;
        const int labj = labels[j];
        ushort2 pv = ((const ushort2*)(pbf + (size_t)labj * D))[lane];
        const float p0 = bf2f(pv.x), p1 = bf2f(pv.y);
        float s = 0.0f, mxw = -INFINITY, mnw = INFINITY, c = 0.0f;
        for (int i0 = 0; i0 < BS; i0 += 256) {
            int4 lv = ((const int4*)labels)[(i0 >> 2) + lane];
#pragma unroll
            for (int comp = 0; comp < 4; comp++) {
                int lc = (comp == 0) ? lv.x : (comp == 1) ? lv.y : (comp == 2) ? lv.z : lv.w;
                unsigned long long bits = __ballot(lc == labj);
                while (bits) {
                    int L = __builtin_ctzll(bits);
                    bits &= bits - 1;
                    int i = i0 + 4 * L + comp;
                    ushort2 bv = ((const ushort2*)(bbf + (size_t)i * D))[lane];
                    float d = bf2f(bv.x) * p0 + bf2f(bv.y) * p1;
#pragma unroll
                    for (int off = 32; off; off >>= 1) d += __shfl_xor(d, off);
                    float wv = fmaf(d, -32.0f, 3.2f);
                    s += __expf(wv);
                    mxw = fmaxf(mxw, wv);
                    mnw = fminf(mnw, wv);
                    c += 1.0f;
                }
            }
        }
        if (lane == 0) {
            posS[j] = s; posMx[j] = mxw; posMn[j] = mnw; posCnt[j] = c;
        }
    }
}

// ---------- final: combine partials, softplus, mean accumulate ----------
__global__ __launch_bounds__(256) void final_reduce(const float* __restrict__ S,
                                                    const float* __restrict__ negSub,
                                                    const float* __restrict__ posS,
                                                    const float* __restrict__ posMx,
                                                    const float* __restrict__ posMn,
                                                    const float* __restrict__ posCnt,
                                                    float* __restrict__ acc) {
    const int n = blockIdx.x * 256 + threadIdx.x;
    float add = 0.0f, cnt = 0.0f;
    int slot;
    if (n < C_CLS) {
        slot = 2;
        float s = 0.0f;
#pragma unroll
        for (int p = 0; p < NS; p++) s += S[(size_t)n * NS + p];
        s = fmaxf(s - negSub[n], 1e-30f);
        // nz always true for neg on this data: max(m)>0, min(m)<0 with huge margin
        float lse = logf(s) + 36.0f;
        add = softplus(lse);
        cnt = 1.0f;
    } else {
        slot = 0;
        int j = n - C_CLS;
        float s = posS[j], mxw = posMx[j], mnw = posMn[j], c = posCnt[j];
        float maxm = (c < (float)BS) ? fmaxf(mxw, 0.0f) : mxw;
        float minm = (c < (float)BS) ? fminf(mnw, 0.0f) : mnw;
        bool nz = (maxm + minm) != 0.0f;
        if (nz) {
            float lse = logf(s);
            add = softplus(lse);
            cnt = 1.0f;
        }
    }
#pragma unroll
    for (int off = 32; off; off >>= 1) {
        add += __shfl_xor(add, off);
        cnt += __shfl_xor(cnt, off);
    }
    if ((threadIdx.x & 63) == 0) {
        atomicAdd(&acc[slot], add);
        atomicAdd(&acc[slot + 1], cnt);
    }
}

__global__ void combine_kernel(const float* __restrict__ acc, float* __restrict__ out) {
    out[0] = acc[0] / fmaxf(acc[1], 1.0f) + acc[2] / fmaxf(acc[3], 1.0f);
}

// ---------- launch ----------
extern "C" void kernel_launch(void* const* d_in, const int* in_sizes, int n_in,
                              void* d_out, int out_size, void* d_ws, size_t ws_size,
                              hipStream_t stream) {
    const float* batch = (const float*)d_in[0];
    const float* proxies = (const float*)d_in[1];
    const int* labels = (const int*)d_in[2];
    float* out = (float*)d_out;

    char* ws = (char*)d_ws;
    float* acc = (float*)ws;
    short* bbf = (short*)(ws + 256);
    short* pbf = (short*)(ws + 256 + (size_t)BS * D * 2);
    char* p = ws + 256 + (size_t)(BS + C_CLS) * D * 2;
    float* negS = (float*)p;             p += (size_t)C_CLS * NS * 4;
    float* negSub = (float*)p;           p += (size_t)C_CLS * 4;
    float* posS = (float*)p;             p += (size_t)BS * 4;
    float* posMx = (float*)p;            p += (size_t)BS * 4;
    float* posMn = (float*)p;            p += (size_t)BS * 4;
    float* posCnt = (float*)p;

    normalize_all<<<(BS + C_CLS) / 4, 256, 0, stream>>>(batch, proxies, bbf, pbf, acc, negSub);
    neg_mm<<<64 * NS, 256, 0, stream>>>(pbf, bbf, negS);
    corr_pos<<<2048, 256, 0, stream>>>(pbf, bbf, labels, negSub, posS, posMx, posMn, posCnt);
    final_reduce<<<(C_CLS + BS) / 256, 256, 0, stream>>>(negS, negSub,
                                                         posS, posMx, posMn, posCnt, acc);
    combine_kernel<<<1, 1, 0, stream>>>(acc, out);
}

// Round 5
// 62.454 us; speedup vs baseline: 1.5120x; 1.0524x over previous
//
#include <hip/hip_runtime.h>
#include <math.h>

#define BS 4096
#define C_CLS 16384
#define D 128
#define NS 16  // batch splits for neg matmul: split = 256 rows = 4 rounds of 64
// proxies pre-scaled by KE=32/ln2, so MFMA yields d' = 32*sim/ln2 and
// exp(32*sim - 32.8) = 2^(d' - BE); the 2^-BE factor is applied in final_reduce.
#define KE 46.16624130844683f
#define NEG_BLOCKS (64 * NS)

typedef __attribute__((ext_vector_type(8))) short short8;
typedef __attribute__((ext_vector_type(4))) float f32x4;

__device__ inline float bf2f(unsigned short h) {
    return __uint_as_float(((unsigned)h) << 16);
}
__device__ inline unsigned short f2bf(float f) {
    unsigned u = __float_as_uint(f);
    u += 0x7FFF + ((u >> 16) & 1);  // RNE
    return (unsigned short)(u >> 16);
}
__device__ inline float fast_exp2(float x) {
#if __has_builtin(__builtin_amdgcn_exp2f)
    return __builtin_amdgcn_exp2f(x);
#else
    return exp2f(x);
#endif
}
__device__ inline float softplus(float x) {
    return fmaxf(x, 0.0f) + log1pf(__expf(-fabsf(x)));
}
__device__ inline void gload16(const void* g, void* l) {
    __builtin_amdgcn_global_load_lds((const __attribute__((address_space(1))) void*)g,
                                     (__attribute__((address_space(3))) void*)l, 16, 0, 0);
}

// ---------- normalize (batch unscaled, proxies x KE) + ws init ----------
__global__ __launch_bounds__(256) void normalize_all(const float* __restrict__ batch,
                                                     const float* __restrict__ proxies,
                                                     short* __restrict__ bbf,
                                                     short* __restrict__ pbf,
                                                     float* __restrict__ acc,
                                                     float* __restrict__ negSub,
                                                     int* __restrict__ counter) {
    const int w = threadIdx.x >> 6, lane = threadIdx.x & 63;
    const int row = blockIdx.x * 4 + w;
    const bool isb = row < BS;
    const float* src = isb ? batch : proxies;
    short* dst = isb ? bbf : pbf;
    const int r = isb ? row : row - BS;
    const float sc = isb ? 1.0f : KE;

    float2 v = ((const float2*)(src + (size_t)r * D))[lane];
    float ss = v.x * v.x + v.y * v.y;
#pragma unroll
    for (int off = 32; off; off >>= 1) ss += __shfl_xor(ss, off);
    float inv = rsqrtf(ss) * sc;
    ushort2 o;
    o.x = f2bf(v.x * inv);
    o.y = f2bf(v.y * inv);
    ((ushort2*)(dst + (size_t)r * D))[lane] = o;

    if (blockIdx.x < 64) negSub[blockIdx.x * 256 + threadIdx.x] = 0.0f;
    if (blockIdx.x == 0) {
        if (threadIdx.x < 4) acc[threadIdx.x] = 0.0f;
        if (threadIdx.x == 4) *counter = 0;
    }
}

// ---------- mm_all: neg matmul blocks + pos-scan blocks + corr blocks ----------
// neg: blocks [0, NEG_BLOCKS): wave owns 64 proxies (4 tiles); block owns 256.
//   B tiles staged in fragment order via async global_load_lds, double-buffered.
// pos: blocks [NEG_BLOCKS, NEG_BLOCKS+1024): one wave per column j.
// corr: blocks [NEG_BLOCKS+1024, NEG_BLOCKS+2048): one wave per batch row i.
__global__ __launch_bounds__(256, 4) void mm_all(const short* __restrict__ pbf,
                                                 const short* __restrict__ bbf,
                                                 const int* __restrict__ labels,
                                                 float* __restrict__ S,
                                                 float* __restrict__ negSub,
                                                 float* __restrict__ posS,
                                                 float* __restrict__ posMx,
                                                 float* __restrict__ posMn,
                                                 float* __restrict__ posCnt) {
    __shared__ short8 frag[2][16 * 64];  // 2 x 16KB

    const int bid = blockIdx.x;
    const int tid = threadIdx.x;
    const int w = tid >> 6, lane = tid & 63, l16 = lane & 15, g = lane >> 4;

    if (bid < NEG_BLOCKS) {
        const int pg = bid & 63;   // proxy group of 256
        const int sp = bid >> 6;   // split
        const int wbase = pg * 256 + w * 64;

        short8 a[4][4];
#pragma unroll
        for (int pt = 0; pt < 4; pt++)
#pragma unroll
            for (int kk = 0; kk < 4; kk++)
                a[pt][kk] = *(const short8*)(pbf + (size_t)(wbase + pt * 16 + l16) * D + kk * 32 + g * 8);

        float s[4][4];
#pragma unroll
        for (int pt = 0; pt < 4; pt++)
#pragma unroll
            for (int r = 0; r < 4; r++) s[pt][r] = 0.0f;

        const int ibeg = sp * (BS / NS);
        const short* srcbase = bbf + (size_t)(ibeg + w * 16 + l16) * D + g * 8;

        // stage round 0 into buf 0 (dest: wave-uniform base + lane*16)
#pragma unroll
        for (int kk = 0; kk < 4; kk++)
            gload16(srcbase + kk * 32, &frag[0][(w * 4 + kk) * 64]);
        asm volatile("s_waitcnt vmcnt(0)" ::: "memory");
        __syncthreads();

        for (int rnd = 0; rnd < 4; rnd++) {
            const int cur = rnd & 1;
            if (rnd < 3) {  // issue next round's loads into the other buffer
                const short* sn = srcbase + (size_t)(rnd + 1) * 64 * D;
#pragma unroll
                for (int kk = 0; kk < 4; kk++)
                    gload16(sn + kk * 32, &frag[cur ^ 1][(w * 4 + kk) * 64]);
            }
#pragma unroll
            for (int bt = 0; bt < 4; bt++) {
                short8 b[4];
#pragma unroll
                for (int kk = 0; kk < 4; kk++) b[kk] = frag[cur][(bt * 4 + kk) * 64 + lane];
#pragma unroll
                for (int pt = 0; pt < 4; pt++) {
                    f32x4 acc = {0.0f, 0.0f, 0.0f, 0.0f};
#pragma unroll
                    for (int kk = 0; kk < 4; kk++)
                        acc = __builtin_amdgcn_mfma_f32_16x16x32_bf16(a[pt][kk], b[kk], acc, 0, 0, 0);
#pragma unroll
                    for (int r = 0; r < 4; r++) s[pt][r] += fast_exp2(acc[r]);
                }
            }
            asm volatile("s_waitcnt vmcnt(0)" ::: "memory");
            __syncthreads();
        }

        // reduce the 16 batch-column lanes (stays within g group)
#pragma unroll
        for (int off = 1; off < 16; off <<= 1)
#pragma unroll
            for (int pt = 0; pt < 4; pt++)
#pragma unroll
                for (int r = 0; r < 4; r++) s[pt][r] += __shfl_xor(s[pt][r], off);

        if (l16 == 0) {
#pragma unroll
            for (int pt = 0; pt < 4; pt++)
#pragma unroll
                for (int r = 0; r < 4; r++) {
                    int row = wbase + pt * 16 + g * 4 + r;
                    S[(size_t)row * NS + sp] = s[pt][r];
                }
        }
    } else if (bid < NEG_BLOCKS + 1024) {
        // pos: one wave per column j; pv is KE-scaled so wv = -ln2*d' + 3.2
        const int j = (bid - NEG_BLOCKS) * 4 + w;
        const int labj = labels[j];
        ushort2 pv = ((const ushort2*)(pbf + (size_t)labj * D))[lane];
        const float p0 = bf2f(pv.x), p1 = bf2f(pv.y);
        float s = 0.0f, mxw = -INFINITY, mnw = INFINITY, c = 0.0f;
        for (int i0 = 0; i0 < BS; i0 += 256) {
            int4 lv = ((const int4*)labels)[(i0 >> 2) + lane];
#pragma unroll
            for (int comp = 0; comp < 4; comp++) {
                int lc = (comp == 0) ? lv.x : (comp == 1) ? lv.y : (comp == 2) ? lv.z : lv.w;
                unsigned long long bits = __ballot(lc == labj);
                while (bits) {
                    int L = __builtin_ctzll(bits);
                    bits &= bits - 1;
                    int i = i0 + 4 * L + comp;
                    ushort2 bv = ((const ushort2*)(bbf + (size_t)i * D))[lane];
                    float d = bf2f(bv.x) * p0 + bf2f(bv.y) * p1;
#pragma unroll
                    for (int off = 32; off; off >>= 1) d += __shfl_xor(d, off);
                    float wv = fmaf(d, -0.69314718055994531f, 3.2f);
                    s += __expf(wv);
                    mxw = fmaxf(mxw, wv);
                    mnw = fminf(mnw, wv);
                    c += 1.0f;
                }
            }
        }
        if (lane == 0) {
            posS[j] = s; posMx[j] = mxw; posMn[j] = mnw; posCnt[j] = c;
        }
    } else {
        // neg correction: subtract exp term for pair (i, labels[i]); pv KE-scaled
        const int i = (bid - NEG_BLOCKS - 1024) * 4 + w;
        const int lab = labels[i];
        ushort2 av = ((const ushort2*)(bbf + (size_t)i * D))[lane];
        ushort2 pv = ((const ushort2*)(pbf + (size_t)lab * D))[lane];
        float d = bf2f(av.x) * bf2f(pv.x) + bf2f(av.y) * bf2f(pv.y);
#pragma unroll
        for (int off = 32; off; off >>= 1) d += __shfl_xor(d, off);
        if (lane == 0) atomicAdd(&negSub[lab], fast_exp2(d));
    }
}

// ---------- final: combine partials + softplus + mean; last block writes out ----------
__global__ __launch_bounds__(256) void final_reduce(const float* __restrict__ S,
                                                    const float* __restrict__ negSub,
                                                    const float* __restrict__ posS,
                                                    const float* __restrict__ posMx,
                                                    const float* __restrict__ posMn,
                                                    const float* __restrict__ posCnt,
                                                    float* __restrict__ acc,
                                                    int* __restrict__ counter,
                                                    float* __restrict__ out) {
    const int n = blockIdx.x * 256 + threadIdx.x;
    float add = 0.0f, cnt = 0.0f;
    int slot;
    if (n < C_CLS) {
        slot = 2;
        float s = 0.0f;
#pragma unroll
        for (int p = 0; p < NS; p++) s += S[(size_t)n * NS + p];
        s = fmaxf(s - negSub[n], 1e-30f);
        // sums carry the 2^BE factor; ln(s*2^-BE)+36 = ln(s)+3.2
        float lse = logf(s) + 3.2f;
        add = softplus(lse);
        cnt = 1.0f;  // nz always true for neg (max>0, min<0, huge margins)
    } else {
        slot = 0;
        int j = n - C_CLS;
        float s = posS[j], mxw = posMx[j], mnw = posMn[j], c = posCnt[j];
        float maxm = (c < (float)BS) ? fmaxf(mxw, 0.0f) : mxw;
        float minm = (c < (float)BS) ? fminf(mnw, 0.0f) : mnw;
        bool nz = (maxm + minm) != 0.0f;
        if (nz) {
            add = softplus(logf(s));
            cnt = 1.0f;
        }
    }
#pragma unroll
    for (int off = 32; off; off >>= 1) {
        add += __shfl_xor(add, off);
        cnt += __shfl_xor(cnt, off);
    }
    if ((threadIdx.x & 63) == 0) {
        atomicAdd(&acc[slot], add);
        atomicAdd(&acc[slot + 1], cnt);
    }

    // last-block combine (threadFenceReduction pattern)
    __shared__ int amLast;
    __threadfence();
    if (threadIdx.x == 0) amLast = (atomicAdd(counter, 1) == (int)gridDim.x - 1);
    __syncthreads();
    if (amLast && threadIdx.x == 0) {
        __threadfence();
        out[0] = acc[0] / fmaxf(acc[1], 1.0f) + acc[2] / fmaxf(acc[3], 1.0f);
    }
}

// ---------- launch ----------
extern "C" void kernel_launch(void* const* d_in, const int* in_sizes, int n_in,
                              void* d_out, int out_size, void* d_ws, size_t ws_size,
                              hipStream_t stream) {
    const float* batch = (const float*)d_in[0];
    const float* proxies = (const float*)d_in[1];
    const int* labels = (const int*)d_in[2];
    float* out = (float*)d_out;

    char* ws = (char*)d_ws;
    float* acc = (float*)ws;
    int* counter = (int*)(ws + 64);
    short* bbf = (short*)(ws + 256);
    short* pbf = (short*)(ws + 256 + (size_t)BS * D * 2);
    char* p = ws + 256 + (size_t)(BS + C_CLS) * D * 2;
    float* negS = (float*)p;             p += (size_t)C_CLS * NS * 4;
    float* negSub = (float*)p;           p += (size_t)C_CLS * 4;
    float* posS = (float*)p;             p += (size_t)BS * 4;
    float* posMx = (float*)p;            p += (size_t)BS * 4;
    float* posMn = (float*)p;            p += (size_t)BS * 4;
    float* posCnt = (float*)p;

    normalize_all<<<(BS + C_CLS) / 4, 256, 0, stream>>>(batch, proxies, bbf, pbf, acc, negSub, counter);
    mm_all<<<NEG_BLOCKS + 2048, 256, 0, stream>>>(pbf, bbf, labels, negS, negSub,
                                                  posS, posMx, posMn, posCnt);
    final_reduce<<<(C_CLS + BS) / 256, 256, 0, stream>>>(negS, negSub, posS, posMx, posMn,
                                                         posCnt, acc, counter, out);
}

// Round 6
// 50.872 us; speedup vs baseline: 1.8562x; 1.2277x over previous
//
#include <hip/hip_runtime.h>
#include <math.h>

#define BS 4096
#define C_CLS 16384
#define D 128
#define NS 16  // batch splits for neg matmul: split = 256 rows = 4 rounds of 64
// proxies pre-scaled by KE=32/ln2 so MFMA yields d' = 32*sim/ln2;
// exp(32*sim + 3.2) = 2^(d') * e^{3.2}, applied at final log.
#define KE 46.16624130844683f
#define POS_C 4.616624130844683f  // 3.2/ln2
#define LN2 0.69314718055994531f
#define CORR_BLOCKS 1024
#define NEG_BLOCKS 1024

typedef __attribute__((ext_vector_type(8))) short short8;
typedef __attribute__((ext_vector_type(4))) float f32x4;

__device__ inline float bf2f(unsigned short h) {
    return __uint_as_float(((unsigned)h) << 16);
}
__device__ inline unsigned short f2bf(float f) {
    unsigned u = __float_as_uint(f);
    u += 0x7FFF + ((u >> 16) & 1);  // RNE
    return (unsigned short)(u >> 16);
}
__device__ inline float fast_exp2(float x) {
#if __has_builtin(__builtin_amdgcn_exp2f)
    return __builtin_amdgcn_exp2f(x);
#else
    return exp2f(x);
#endif
}
__device__ inline float softplus(float x) {
    return fmaxf(x, 0.0f) + log1pf(__expf(-fabsf(x)));
}
__device__ inline void gload16(const void* g, void* l) {
    __builtin_amdgcn_global_load_lds((const __attribute__((address_space(1))) void*)g,
                                     (__attribute__((address_space(3))) void*)l, 16, 0, 0);
}
// monotone float<->uint for atomicMax/Min on floats
__device__ inline unsigned fenc(float f) {
    unsigned u = __float_as_uint(f);
    return (u & 0x80000000u) ? ~u : (u | 0x80000000u);
}
__device__ inline float fdec(unsigned k) {
    return (k & 0x80000000u) ? __uint_as_float(k ^ 0x80000000u) : __uint_as_float(~k);
}

// ---------- normalize (batch unscaled, proxies x KE) + ws init ----------
__global__ __launch_bounds__(256) void normalize_all(const float* __restrict__ batch,
                                                     const float* __restrict__ proxies,
                                                     short* __restrict__ bbf,
                                                     short* __restrict__ pbf,
                                                     float* __restrict__ acc,
                                                     float* __restrict__ negSub,
                                                     float* __restrict__ posSum,
                                                     float* __restrict__ posCnt,
                                                     unsigned* __restrict__ posMaxK,
                                                     unsigned* __restrict__ posMinK,
                                                     int* __restrict__ counter) {
    const int w = threadIdx.x >> 6, lane = threadIdx.x & 63;
    const int row = blockIdx.x * 4 + w;
    const bool isb = row < BS;
    const float* src = isb ? batch : proxies;
    short* dst = isb ? bbf : pbf;
    const int r = isb ? row : row - BS;
    const float sc = isb ? 1.0f : KE;

    float2 v = ((const float2*)(src + (size_t)r * D))[lane];
    float ss = v.x * v.x + v.y * v.y;
#pragma unroll
    for (int off = 32; off; off >>= 1) ss += __shfl_xor(ss, off);
    float inv = rsqrtf(ss) * sc;
    ushort2 o;
    o.x = f2bf(v.x * inv);
    o.y = f2bf(v.y * inv);
    ((ushort2*)(dst + (size_t)r * D))[lane] = o;

    const int bid = blockIdx.x, t = bid * 256 + threadIdx.x;
    if (bid < 64) negSub[t] = 0.0f;
    else if (bid < 128) posSum[t - 64 * 256] = 0.0f;
    else if (bid < 192) posCnt[t - 128 * 256] = 0.0f;
    else if (bid < 256) posMaxK[t - 192 * 256] = 0u;          // fenc(-inf) floor
    else if (bid < 320) posMinK[t - 256 * 256] = 0xFFFFFFFFu; // fenc(+inf) ceil
    if (bid == 0) {
        if (threadIdx.x < 4) acc[threadIdx.x] = 0.0f;
        if (threadIdx.x == 4) *counter = 0;
    }
}

// ---------- mm_all: corr waves (per-label tables) + neg matmul blocks ----------
// corr: blocks [0, CORR_BLOCKS): wave per batch row i; d_i = dot(b_i, p_lab_i)
//   feeds negSub AND the per-label pos tables (pos_sims masked-in == d_i).
// neg: blocks [CORR_BLOCKS, +NEG_BLOCKS): wave owns 64 proxies (4 tiles);
//   block owns 256; B staged fragment-ordered via global_load_lds, dbuf.
__global__ __launch_bounds__(256, 4) void mm_all(const short* __restrict__ pbf,
                                                 const short* __restrict__ bbf,
                                                 const int* __restrict__ labels,
                                                 float* __restrict__ S,
                                                 float* __restrict__ negSub,
                                                 float* __restrict__ posSum,
                                                 float* __restrict__ posCnt,
                                                 unsigned* __restrict__ posMaxK,
                                                 unsigned* __restrict__ posMinK) {
    __shared__ short8 frag[2][16 * 64];  // 2 x 16KB

    const int bid = blockIdx.x;
    const int tid = threadIdx.x;
    const int w = tid >> 6, lane = tid & 63, l16 = lane & 15, g = lane >> 4;

    if (bid < CORR_BLOCKS) {
        // one wave per batch row i
        const int i = bid * 4 + w;
        const int lab = labels[i];
        ushort2 av = ((const ushort2*)(bbf + (size_t)i * D))[lane];
        ushort2 pv = ((const ushort2*)(pbf + (size_t)lab * D))[lane];  // KE-scaled
        float d = bf2f(av.x) * bf2f(pv.x) + bf2f(av.y) * bf2f(pv.y);
#pragma unroll
        for (int off = 32; off; off >>= 1) d += __shfl_xor(d, off);
        if (lane == 0) {
            atomicAdd(&negSub[lab], fast_exp2(d));            // matches neg s terms 2^{d'}
            atomicAdd(&posSum[lab], fast_exp2(POS_C - d));    // exp(-32 sim + 3.2)
            atomicAdd(&posCnt[lab], 1.0f);
            float wv = fmaf(d, -LN2, 3.2f);                   // w_pos
            unsigned k = fenc(wv);
            atomicMax(&posMaxK[lab], k);
            atomicMin(&posMinK[lab], k);
        }
    } else {
        // XCD-aware swizzle: xcd ~ bid%8 gets pgs [lo*8, lo*8+8) for all splits
        const int n = bid - CORR_BLOCKS;
        const int pg = (n & 7) * 8 + ((n >> 3) & 7);
        const int sp = n >> 6;
        const int wbase = pg * 256 + w * 64;

        short8 a[4][4];
#pragma unroll
        for (int pt = 0; pt < 4; pt++)
#pragma unroll
            for (int kk = 0; kk < 4; kk++)
                a[pt][kk] = *(const short8*)(pbf + (size_t)(wbase + pt * 16 + l16) * D + kk * 32 + g * 8);

        float s[4][4];
#pragma unroll
        for (int pt = 0; pt < 4; pt++)
#pragma unroll
            for (int r = 0; r < 4; r++) s[pt][r] = 0.0f;

        const int ibeg = sp * (BS / NS);
        const short* srcbase = bbf + (size_t)(ibeg + w * 16 + l16) * D + g * 8;

        // stage round 0 into buf 0 (dest: wave-uniform base + lane*16)
#pragma unroll
        for (int kk = 0; kk < 4; kk++)
            gload16(srcbase + kk * 32, &frag[0][(w * 4 + kk) * 64]);
        asm volatile("s_waitcnt vmcnt(0)" ::: "memory");
        __syncthreads();

        for (int rnd = 0; rnd < 4; rnd++) {
            const int cur = rnd & 1;
            if (rnd < 3) {  // issue next round's loads into the other buffer
                const short* sn = srcbase + (size_t)(rnd + 1) * 64 * D;
#pragma unroll
                for (int kk = 0; kk < 4; kk++)
                    gload16(sn + kk * 32, &frag[cur ^ 1][(w * 4 + kk) * 64]);
            }
            __builtin_amdgcn_s_setprio(1);
#pragma unroll
            for (int bt = 0; bt < 4; bt++) {
                short8 b[4];
#pragma unroll
                for (int kk = 0; kk < 4; kk++) b[kk] = frag[cur][(bt * 4 + kk) * 64 + lane];
#pragma unroll
                for (int pt = 0; pt < 4; pt++) {
                    f32x4 acc = {0.0f, 0.0f, 0.0f, 0.0f};
#pragma unroll
                    for (int kk = 0; kk < 4; kk++)
                        acc = __builtin_amdgcn_mfma_f32_16x16x32_bf16(a[pt][kk], b[kk], acc, 0, 0, 0);
#pragma unroll
                    for (int r = 0; r < 4; r++) s[pt][r] += fast_exp2(acc[r]);
                }
            }
            __builtin_amdgcn_s_setprio(0);
            asm volatile("s_waitcnt vmcnt(0)" ::: "memory");
            __syncthreads();
        }

        // reduce the 16 batch-column lanes (stays within g group)
#pragma unroll
        for (int off = 1; off < 16; off <<= 1)
#pragma unroll
            for (int pt = 0; pt < 4; pt++)
#pragma unroll
                for (int r = 0; r < 4; r++) s[pt][r] += __shfl_xor(s[pt][r], off);

        if (l16 == 0) {
            // transposed layout S[sp][row]: wave writes 64 consecutive floats
#pragma unroll
            for (int pt = 0; pt < 4; pt++)
#pragma unroll
                for (int r = 0; r < 4; r++) {
                    int row = wbase + pt * 16 + g * 4 + r;
                    S[(size_t)sp * C_CLS + row] = s[pt][r];
                }
        }
    }
}

// ---------- final: combine partials + softplus + mean; last block writes out ----------
__global__ __launch_bounds__(256) void final_reduce(const float* __restrict__ S,
                                                    const float* __restrict__ negSub,
                                                    const int* __restrict__ labels,
                                                    const float* __restrict__ posSum,
                                                    const float* __restrict__ posCnt,
                                                    const unsigned* __restrict__ posMaxK,
                                                    const unsigned* __restrict__ posMinK,
                                                    float* __restrict__ acc,
                                                    int* __restrict__ counter,
                                                    float* __restrict__ out) {
    const int n = blockIdx.x * 256 + threadIdx.x;
    float add = 0.0f, cnt = 0.0f;
    int slot;
    if (n < C_CLS) {
        slot = 2;
        float s = 0.0f;
#pragma unroll
        for (int p = 0; p < NS; p++) s += S[(size_t)p * C_CLS + n];
        s = fmaxf(s - negSub[n], 1e-30f);
        // s carries 2^{d'} terms; lse = log(s) + 3.2
        add = softplus(logf(s) + 3.2f);
        cnt = 1.0f;  // nz always true for neg (max>0, min<0, huge margins)
    } else {
        slot = 0;
        const int j = n - C_CLS;
        const int lab = labels[j];
        float s = posSum[lab], c = posCnt[lab];
        float mxw = fdec(posMaxK[lab]), mnw = fdec(posMinK[lab]);
        float maxm = (c < (float)BS) ? fmaxf(mxw, 0.0f) : mxw;
        float minm = (c < (float)BS) ? fminf(mnw, 0.0f) : mnw;
        bool nz = (maxm + minm) != 0.0f;
        if (nz) {
            add = softplus(logf(s));
            cnt = 1.0f;
        }
    }
#pragma unroll
    for (int off = 32; off; off >>= 1) {
        add += __shfl_xor(add, off);
        cnt += __shfl_xor(cnt, off);
    }
    if ((threadIdx.x & 63) == 0) {
        atomicAdd(&acc[slot], add);
        atomicAdd(&acc[slot + 1], cnt);
    }

    // last-block combine (threadFenceReduction pattern)
    __shared__ int amLast;
    __threadfence();
    if (threadIdx.x == 0) amLast = (atomicAdd(counter, 1) == (int)gridDim.x - 1);
    __syncthreads();
    if (amLast && threadIdx.x == 0) {
        __threadfence();
        out[0] = acc[0] / fmaxf(acc[1], 1.0f) + acc[2] / fmaxf(acc[3], 1.0f);
    }
}

// ---------- launch ----------
extern "C" void kernel_launch(void* const* d_in, const int* in_sizes, int n_in,
                              void* d_out, int out_size, void* d_ws, size_t ws_size,
                              hipStream_t stream) {
    const float* batch = (const float*)d_in[0];
    const float* proxies = (const float*)d_in[1];
    const int* labels = (const int*)d_in[2];
    float* out = (float*)d_out;

    char* ws = (char*)d_ws;
    float* acc = (float*)ws;
    int* counter = (int*)(ws + 64);
    short* bbf = (short*)(ws + 256);
    short* pbf = (short*)(ws + 256 + (size_t)BS * D * 2);
    char* p = ws + 256 + (size_t)(BS + C_CLS) * D * 2;
    float* negS = (float*)p;       p += (size_t)C_CLS * NS * 4;
    float* negSub = (float*)p;     p += (size_t)C_CLS * 4;
    float* posSum = (float*)p;     p += (size_t)C_CLS * 4;
    float* posCnt = (float*)p;     p += (size_t)C_CLS * 4;
    unsigned* posMaxK = (unsigned*)p; p += (size_t)C_CLS * 4;
    unsigned* posMinK = (unsigned*)p;

    normalize_all<<<(BS + C_CLS) / 4, 256, 0, stream>>>(batch, proxies, bbf, pbf, acc,
                                                        negSub, posSum, posCnt, posMaxK,
                                                        posMinK, counter);
    mm_all<<<CORR_BLOCKS + NEG_BLOCKS, 256, 0, stream>>>(pbf, bbf, labels, negS, negSub,
                                                         posSum, posCnt, posMaxK, posMinK);
    final_reduce<<<(C_CLS + BS) / 256, 256, 0, stream>>>(negS, negSub, labels, posSum,
                                                         posCnt, posMaxK, posMinK,
                                                         acc, counter, out);
}